// Round 3
// baseline (348.343 us; speedup 1.0000x reference)
//
#include <hip/hip_runtime.h>
#include <stdint.h>

// Attention B=2,H=16,S=2048,D=64 fp32. Round 11: triple-buffered wave-private
// staging + cross-iteration K register-prefetch -> no blocking wait on the
// per-iteration critical path.
//
// r10 post-mortem: 71.9us, MfmaUtil 28 / VALU 31 / HBM 6% => still latency-
// bound. The per-iter chain [vmcnt(4); ds_read K,V (120cy); lgkmcnt(0);
// stage; QK; exp; PV] eats a full ds_read latency + a forced lgkm drain
// before any MFMA, and the memory-clobber asm + double-buffer WAR blocks
// cross-iteration overlap.
//
// Fix:
//  - TRIPLE buffer (per wave: 3 x [2KB K + 2KB V], 48KB/block): stage(kt+2)
//    overwrites the buffer read 2 iters ago, whose reads were consumed by
//    MFMAs (compiler-inserted lgkm waits) -> the in-loop lgkmcnt(0) drain is
//    replaced by a free counted lgkmcnt(4) ordering stage vs older reads.
//  - K REGISTER PREFETCH: tile kt+1's K fragments are ds_read at the END of
//    body kt, after vmcnt(4) proves its DMA landed; body kt+1's QK then
//    starts on register-resident operands. The ds_read latency hides under
//    exp+PV of the current tile.
//  Steady body: QK(kt)[regs] -> V-reads(kt) -> lgkm(4) -> stage(kt+2) ->
//               exp(kt) -> vmcnt(4) -> K-prefetch(kt+1) -> PV(kt).
//  vmcnt(4): outstanding = stages for kt+1 (4) + kt+2 (4); wait to 4 =>
//  kt+1 landed, kt+2 still in flight. Tail (kt=30) uses vmcnt(0) since only
//  tile31's 4 loads are outstanding. No barrier until the epilogue.
//
// Occupancy: 48KB LDS -> 3 blocks/CU; regs ~156 (<=170 @ waves/EU=3) -> 3.
// Same as r10, so the pipeline fill is pure win.
//
// Per-wave LDS layouts (unchanged):
//   K [16 rows=keys][8 slots of 16B]: row r slot s holds d-octet s^(r&7)
//   V [64 rows=d][2 slots of 16B]:    row d slot s holds key-chunk s^((d>>2)&1)
// Swizzles applied on the GLOBAL gather side of the DMA; fragment reads are
// <=2-way banked (free, m136).

typedef _Float16 f16;
typedef __attribute__((ext_vector_type(4))) _Float16 f16x4;
typedef __attribute__((ext_vector_type(8))) _Float16 f16x8;
typedef __attribute__((ext_vector_type(4))) float f32x4;

constexpr int Bc = 2, Hc = 16, Sc = 2048, Dc = 64;
constexpr size_t NE = (size_t)Bc * Hc * Sc * Dc;

__device__ inline void gld_lds16(const f16* g, f16* l) {
  __builtin_amdgcn_global_load_lds(
      (const __attribute__((address_space(1))) unsigned int*)g,
      (__attribute__((address_space(3))) unsigned int*)l, 16, 0, 0);
}

// ---------------- prep: K*scale -> f16; V -> f16 transposed (unchanged) ---
__global__ __launch_bounds__(256)
void prep(const float* __restrict__ kp, const float* __restrict__ vp,
          const float* __restrict__ temp,
          f16* __restrict__ kh, f16* __restrict__ vt) {
  const int tid = threadIdx.x;
  const int bh = blockIdx.x & 31;
  const int st = blockIdx.x >> 5;
  const float ksc = 1.44269504088896340736f / (temp[0] * 8.0f);

  const size_t base = (size_t)bh * Sc * Dc + (size_t)st * 64 * Dc;
  const float* kg = kp + base;
  f16* khg = kh + base;
#pragma unroll
  for (int i = 0; i < 4; ++i) {
    int f = tid + (i << 8);
    f32x4 a = *(const f32x4*)(kg + f * 4);
    *(f16x4*)(khg + f * 4) = (f16x4){(f16)(a.x * ksc), (f16)(a.y * ksc),
                                     (f16)(a.z * ksc), (f16)(a.w * ksc)};
  }
  const int sb = tid & 15, db = tid >> 4;
  const float* vg = vp + base;
  f32x4 r0 = *(const f32x4*)(vg + (4 * sb + 0) * Dc + 4 * db);
  f32x4 r1 = *(const f32x4*)(vg + (4 * sb + 1) * Dc + 4 * db);
  f32x4 r2 = *(const f32x4*)(vg + (4 * sb + 2) * Dc + 4 * db);
  f32x4 r3 = *(const f32x4*)(vg + (4 * sb + 3) * Dc + 4 * db);
  f16* vtg = vt + (size_t)bh * Dc * Sc + (size_t)st * 64 + 4 * sb;
  *(f16x4*)(vtg + (size_t)(4 * db + 0) * Sc) = (f16x4){(f16)r0.x, (f16)r1.x, (f16)r2.x, (f16)r3.x};
  *(f16x4*)(vtg + (size_t)(4 * db + 1) * Sc) = (f16x4){(f16)r0.y, (f16)r1.y, (f16)r2.y, (f16)r3.y};
  *(f16x4*)(vtg + (size_t)(4 * db + 2) * Sc) = (f16x4){(f16)r0.z, (f16)r1.z, (f16)r2.z, (f16)r3.z};
  *(f16x4*)(vtg + (size_t)(4 * db + 3) * Sc) = (f16x4){(f16)r0.w, (f16)r1.w, (f16)r2.w, (f16)r3.w};
}

// ---------------- fa11: triple-buffer + K reg-prefetch --------------------
__global__ __launch_bounds__(256, 3)
void fa11(const float* __restrict__ qp, const f16* __restrict__ kh,
          const f16* __restrict__ vt, float* __restrict__ out) {
  // union: staging (4 waves x 3 bufs x [2KB K + 2KB V] = 48KB) /
  //        epilogue (2x 64x66 f32 = 33792B)
  __shared__ __align__(16) char smem[49152];
  __shared__ float Lred[4][64];

  const int tid = threadIdx.x, lane = tid & 63, w = tid >> 6;
  const int lq = lane & 15, qd = lane >> 4;
  const int L = blockIdx.x;
  const int bh = L & 31;                   // blockIdx%8 == bh%8 (XCD-affine)
  const int qt = L >> 5;

  const size_t base = (size_t)bh * Sc * Dc;

  // per-wave staging buffers (f16 units): 3 bufs of 1024 f16 each region
  f16* Kw = (f16*)smem + w * 3072;                 // [3][1024]
  f16* Vw = (f16*)(smem + 24576) + w * 3072;       // [3][1024]

  // ---- staging gather addresses (swizzle on the global side) ----
  const int oct = (lane & 7) ^ ((lane >> 3) & 7);
  const f16* kg0 = kh + base + (size_t)(16 * w + (lane >> 3)) * 64 + oct * 8;
  const f16* kg1 = kg0 + 8 * 64;
  const int vd = lane >> 1;
  const int vc = (lane & 1) ^ ((lane >> 3) & 1);
  const f16* vg0 = vt + (size_t)bh * Dc * Sc + (size_t)vd * Sc + 16 * w + vc * 8;
  const f16* vg1 = vg0 + (size_t)32 * Sc;

  auto stage = [&](int kt, int b) {
    gld_lds16(kg0 + (size_t)kt * 4096, Kw + b * 1024);
    gld_lds16(kg1 + (size_t)kt * 4096, Kw + b * 1024 + 512);
    gld_lds16(vg0 + kt * 64, Vw + b * 1024);
    gld_lds16(vg1 + kt * 64, Vw + b * 1024 + 512);
  };

  // ---- fragment LDS offsets (f16 units, constant per lane) ----
  const int koff0 = lq * 64 + ((qd) ^ (lq & 7)) * 8;
  const int koff1 = lq * 64 + ((4 + qd) ^ (lq & 7)) * 8;
  int voff[4];
#pragma unroll
  for (int dt = 0; dt < 4; ++dt)
    voff[dt] = (16 * dt + lq) * 16 + (((qd >> 1) ^ ((lq >> 2) & 1)) << 3) +
               (qd & 1) * 4;

  // ---- Q B-fragments (one-time packed cvt) ----
  const float* qg = qp + base + (size_t)qt * 64 * Dc;
  f16x8 Qf[4][2];
#pragma unroll
  for (int nt = 0; nt < 4; ++nt)
#pragma unroll
    for (int kc = 0; kc < 2; ++kc) {
      const float* p = qg + (16 * nt + lq) * Dc + 32 * kc + 8 * qd;
      f32x4 a = *(const f32x4*)p;
      f32x4 b = *(const f32x4*)(p + 4);
      auto p0 = __builtin_amdgcn_cvt_pkrtz(a.x, a.y);
      auto p1 = __builtin_amdgcn_cvt_pkrtz(a.z, a.w);
      auto p2 = __builtin_amdgcn_cvt_pkrtz(b.x, b.y);
      auto p3 = __builtin_amdgcn_cvt_pkrtz(b.z, b.w);
      f16x8 qf;
      ((decltype(p0)*)&qf)[0] = p0;
      ((decltype(p0)*)&qf)[1] = p1;
      ((decltype(p0)*)&qf)[2] = p2;
      ((decltype(p0)*)&qf)[3] = p3;
      Qf[nt][kc] = qf;
    }

  // pinned zero accumulator source
  float z0 = 0.f, z1 = 0.f, z2 = 0.f, z3 = 0.f;
  asm volatile("" : "+v"(z0), "+v"(z1), "+v"(z2), "+v"(z3));
  const f32x4 Zc = (f32x4){z0, z1, z2, z3};

  f32x4 Oa[4][4];
  float ls[4];
#pragma unroll
  for (int nt = 0; nt < 4; ++nt) {
    ls[nt] = 0.f;
#pragma unroll
    for (int dt = 0; dt < 4; ++dt) Oa[nt][dt] = (f32x4){0.f, 0.f, 0.f, 0.f};
  }

  stage(0, 0);
  stage(1, 1);
  asm volatile("s_waitcnt vmcnt(4)" ::: "memory");   // tile 0 landed
  f16x8 KA0 = *(const f16x8*)(Kw + koff0);           // buf 0
  f16x8 KA1 = *(const f16x8*)(Kw + koff1);
  f16x8 KB0, KB1;

  // Body kt: QK(kt) w/ KC*; V-read(kt) from BUF; lgkm(4); stage(STGKT->SBUF);
  // exp(kt); vmcnt(WN); K-prefetch(kt+1) from NBUF into KP*; PV(kt).
#define FA_BODY(BUF, NBUF, SBUF, STGKT, WN, KC0, KC1, KP0, KP1, DO_PF)        \
  {                                                                           \
    f32x4 St[4];                                                              \
    _Pragma("unroll")                                                         \
    for (int nt = 0; nt < 4; ++nt) {                                          \
      f32x4 a = __builtin_amdgcn_mfma_f32_16x16x32_f16(KC0, Qf[nt][0], Zc, 0, 0, 0); \
      a = __builtin_amdgcn_mfma_f32_16x16x32_f16(KC1, Qf[nt][1], a, 0, 0, 0); \
      St[nt] = a;                                                             \
    }                                                                         \
    const f16* VB = Vw + (BUF) * 1024;                                        \
    f16x4 Vf[4];                                                              \
    _Pragma("unroll")                                                         \
    for (int dt = 0; dt < 4; ++dt) Vf[dt] = *(const f16x4*)(VB + voff[dt]);   \
    asm volatile("s_waitcnt lgkmcnt(4)" ::: "memory");                        \
    if ((STGKT) < 32) stage((STGKT), (SBUF));                                 \
    f16x4 Pf[4];                                                              \
    _Pragma("unroll")                                                         \
    for (int nt = 0; nt < 4; ++nt) {                                          \
      float e0 = __builtin_amdgcn_exp2f(St[nt].x);                            \
      float e1 = __builtin_amdgcn_exp2f(St[nt].y);                            \
      float e2 = __builtin_amdgcn_exp2f(St[nt].z);                            \
      float e3 = __builtin_amdgcn_exp2f(St[nt].w);                            \
      ls[nt] += (e0 + e1) + (e2 + e3);                                        \
      auto lo = __builtin_amdgcn_cvt_pkrtz(e0, e1);                           \
      auto hi = __builtin_amdgcn_cvt_pkrtz(e2, e3);                           \
      f16x4 p;                                                                \
      ((decltype(lo)*)&p)[0] = lo;                                            \
      ((decltype(lo)*)&p)[1] = hi;                                            \
      Pf[nt] = p;                                                             \
    }                                                                         \
    asm volatile("s_waitcnt vmcnt(" WN ")" ::: "memory");                     \
    if (DO_PF) {                                                              \
      const f16* KBn = Kw + (NBUF) * 1024;                                    \
      KP0 = *(const f16x8*)(KBn + koff0);                                     \
      KP1 = *(const f16x8*)(KBn + koff1);                                     \
    }                                                                         \
    _Pragma("unroll")                                                         \
    for (int nt = 0; nt < 4; ++nt)                                            \
      _Pragma("unroll")                                                       \
      for (int dt = 0; dt < 4; ++dt)                                          \
        Oa[nt][dt] = __builtin_amdgcn_mfma_f32_16x16x16f16(Pf[nt], Vf[dt],    \
                                                           Oa[nt][dt], 0, 0, 0); \
  }

#pragma unroll 1
  for (int kt6 = 0; kt6 < 5; ++kt6) {
    const int k0 = 6 * kt6;
    FA_BODY(0, 1, 2, k0 + 2, "4", KA0, KA1, KB0, KB1, 1)   // kt=6i+0
    FA_BODY(1, 2, 0, k0 + 3, "4", KB0, KB1, KA0, KA1, 1)   // kt=6i+1
    FA_BODY(2, 0, 1, k0 + 4, "4", KA0, KA1, KB0, KB1, 1)   // kt=6i+2
    FA_BODY(0, 1, 2, k0 + 5, "4", KB0, KB1, KA0, KA1, 1)   // kt=6i+3
    FA_BODY(1, 2, 0, k0 + 6, "4", KA0, KA1, KB0, KB1, 1)   // kt=6i+4
    FA_BODY(2, 0, 1, k0 + 7, "4", KB0, KB1, KA0, KA1, 1)   // kt=6i+5
  }
  // kt=30: buf 0, no stage, vmcnt(0) (only tile 31's 4 loads outstanding)
  FA_BODY(0, 1, 2, 32, "0", KA0, KA1, KB0, KB1, 1)
  // kt=31: buf 1, no stage, no prefetch
  FA_BODY(1, 2, 0, 32, "0", KB0, KB1, KA0, KA1, 0)

#undef FA_BODY

  // ---- epilogue: row sums + O tree-reduction (staging LDS reused) ----
#pragma unroll
  for (int nt = 0; nt < 4; ++nt) {
    float l = ls[nt];
    l += __shfl_xor(l, 16, 64);
    l += __shfl_xor(l, 32, 64);
    ls[nt] = l;
  }
  __syncthreads();              // all waves done with staging LDS
  if (qd == 0) {
#pragma unroll
    for (int nt = 0; nt < 4; ++nt) Lred[w][16 * nt + lq] = ls[nt];
  }
  float* OsA = (float*)smem;
  float* OsB = (float*)(smem + 16896);
  float* Os = (w & 2) ? OsB : OsA;
  if (!(w & 1)) {
#pragma unroll
    for (int nt = 0; nt < 4; ++nt)
#pragma unroll
      for (int dt = 0; dt < 4; ++dt)
#pragma unroll
        for (int r = 0; r < 4; ++r)
          Os[(16 * nt + 4 * qd + r) * 66 + 16 * dt + lq] = Oa[nt][dt][r];
  }
  __syncthreads();
  if (w & 1) {
#pragma unroll
    for (int nt = 0; nt < 4; ++nt)
#pragma unroll
      for (int dt = 0; dt < 4; ++dt)
#pragma unroll
        for (int r = 0; r < 4; ++r)
          Os[(16 * nt + 4 * qd + r) * 66 + 16 * dt + lq] += Oa[nt][dt][r];
  }
  __syncthreads();

  float* og = out + base + (size_t)qt * 64 * Dc;
#pragma unroll
  for (int r = 0; r < 16; ++r) {
    int row = 16 * w + r;
    float l = Lred[0][row] + Lred[1][row] + Lred[2][row] + Lred[3][row];
    float vo = OsA[row * 66 + lane] + OsB[row * 66 + lane];
    og[(size_t)row * Dc + lane] = vo / l;
  }
}

extern "C" void kernel_launch(void* const* d_in, const int* in_sizes, int n_in,
                              void* d_out, int out_size, void* d_ws, size_t ws_size,
                              hipStream_t stream) {
  const float* q    = (const float*)d_in[0];
  const float* k    = (const float*)d_in[1];
  const float* v    = (const float*)d_in[2];
  const float* temp = (const float*)d_in[3];
  float* out = (float*)d_out;

  f16* kh = (f16*)d_ws;          // 8.4 MB
  f16* vt = kh + NE;             // 8.4 MB

  prep<<<dim3(Bc * Hc * (Sc / 64)), dim3(256), 0, stream>>>(k, v, temp, kh, vt);
  fa11<<<dim3(Bc * Hc * (Sc / 64)), dim3(256), 0, stream>>>(q, kh, vt, out);
}

// Round 4
// 212.247 us; speedup vs baseline: 1.6412x; 1.6412x over previous
//
#include <hip/hip_runtime.h>
#include <stdint.h>

// Attention B=2,H=16,S=2048,D=64 fp32. Round 12: triple-buffered wave-private
// staging, depth-2 prefetch, stage-at-end -> no in-loop lgkm drain, free
// vmcnt waits, ZERO new registers vs the known-good r10.
//
// r11 post-mortem: K reg-prefetch (16 live VGPRs across iters) + 6-deep
// rotated unroll pushed the live set over the 3-waves/EU cap -> spill
// (FETCH 360MB / WRITE 535MB), 267us. Lesson: structure changes must be
// register-neutral. This round keeps r10's body byte-for-byte (same live
// set, ~148 regs) and only changes the buffering discipline:
//
//  - 3 buffers/wave (3 x [2KB K + 2KB V] = 12KB/wave, 48KB/block).
//  - Prologue stages tiles 0,1,2 (12 loads in flight).
//  - Iter kt: s_waitcnt vmcnt(8) -> tile kt landed; it was issued 3 iters
//    (~1800cyc) ago, so the wait is ~always satisfied already (HBM worst
//    case ~900cyc). ds_read K/V fragments from buf kt%3; QK -> exp -> PV;
//    then stage(kt+3) into buf kt%3 AT THE END: the PV/QK operand waits
//    (compiler-inserted lgkm) prove this buffer's reads retired, so the WAR
//    hazard is resolved by program order and the old lgkmcnt(0) drain is
//    DELETED. A zero-cost compiler fence keeps the DMA from hoisting.
//  - Tail: kt=30 waits vmcnt(4), kt=31 vmcnt(0). No barrier until epilogue.
//
// Occupancy: LDS 160/48 -> 3 blocks/CU; regs -> 3 waves/EU. Same as r10, so
// removing ~250cyc/iter of exposed wait is pure win.
//
// Per-wave LDS layouts (unchanged):
//   K [16 rows=keys][8 slots of 16B]: row r slot s holds d-octet s^(r&7)
//   V [64 rows=d][2 slots of 16B]:    row d slot s holds key-chunk s^((d>>2)&1)
// Swizzles applied on the GLOBAL gather side of the DMA; fragment reads are
// <=2-way banked (free, m136).

typedef _Float16 f16;
typedef __attribute__((ext_vector_type(4))) _Float16 f16x4;
typedef __attribute__((ext_vector_type(8))) _Float16 f16x8;
typedef __attribute__((ext_vector_type(4))) float f32x4;

constexpr int Bc = 2, Hc = 16, Sc = 2048, Dc = 64;
constexpr size_t NE = (size_t)Bc * Hc * Sc * Dc;

__device__ inline void gld_lds16(const f16* g, f16* l) {
  __builtin_amdgcn_global_load_lds(
      (const __attribute__((address_space(1))) unsigned int*)g,
      (__attribute__((address_space(3))) unsigned int*)l, 16, 0, 0);
}

// ---------------- prep: K*scale -> f16; V -> f16 transposed (unchanged) ---
__global__ __launch_bounds__(256)
void prep(const float* __restrict__ kp, const float* __restrict__ vp,
          const float* __restrict__ temp,
          f16* __restrict__ kh, f16* __restrict__ vt) {
  const int tid = threadIdx.x;
  const int bh = blockIdx.x & 31;
  const int st = blockIdx.x >> 5;
  const float ksc = 1.44269504088896340736f / (temp[0] * 8.0f);

  const size_t base = (size_t)bh * Sc * Dc + (size_t)st * 64 * Dc;
  const float* kg = kp + base;
  f16* khg = kh + base;
#pragma unroll
  for (int i = 0; i < 4; ++i) {
    int f = tid + (i << 8);
    f32x4 a = *(const f32x4*)(kg + f * 4);
    *(f16x4*)(khg + f * 4) = (f16x4){(f16)(a.x * ksc), (f16)(a.y * ksc),
                                     (f16)(a.z * ksc), (f16)(a.w * ksc)};
  }
  const int sb = tid & 15, db = tid >> 4;
  const float* vg = vp + base;
  f32x4 r0 = *(const f32x4*)(vg + (4 * sb + 0) * Dc + 4 * db);
  f32x4 r1 = *(const f32x4*)(vg + (4 * sb + 1) * Dc + 4 * db);
  f32x4 r2 = *(const f32x4*)(vg + (4 * sb + 2) * Dc + 4 * db);
  f32x4 r3 = *(const f32x4*)(vg + (4 * sb + 3) * Dc + 4 * db);
  f16* vtg = vt + (size_t)bh * Dc * Sc + (size_t)st * 64 + 4 * sb;
  *(f16x4*)(vtg + (size_t)(4 * db + 0) * Sc) = (f16x4){(f16)r0.x, (f16)r1.x, (f16)r2.x, (f16)r3.x};
  *(f16x4*)(vtg + (size_t)(4 * db + 1) * Sc) = (f16x4){(f16)r0.y, (f16)r1.y, (f16)r2.y, (f16)r3.y};
  *(f16x4*)(vtg + (size_t)(4 * db + 2) * Sc) = (f16x4){(f16)r0.z, (f16)r1.z, (f16)r2.z, (f16)r3.z};
  *(f16x4*)(vtg + (size_t)(4 * db + 3) * Sc) = (f16x4){(f16)r0.w, (f16)r1.w, (f16)r2.w, (f16)r3.w};
}

// ---------------- fa12: triple-buffer, stage-at-end, no lgkm drain --------
__global__ __launch_bounds__(256, 3)
void fa12(const float* __restrict__ qp, const f16* __restrict__ kh,
          const f16* __restrict__ vt, float* __restrict__ out) {
  // union: staging (4 waves x 3 bufs x [2KB K + 2KB V] = 48KB) /
  //        epilogue (2x 64x66 f32 = 33792B)
  __shared__ __align__(16) char smem[49152];
  __shared__ float Lred[4][64];

  const int tid = threadIdx.x, lane = tid & 63, w = tid >> 6;
  const int lq = lane & 15, qd = lane >> 4;
  const int L = blockIdx.x;
  const int bh = L & 31;                   // blockIdx%8 == bh%8 (XCD-affine)
  const int qt = L >> 5;

  const size_t base = (size_t)bh * Sc * Dc;

  // per-wave staging buffers (f16 units): 3 bufs x 1024 f16 per region
  f16* Kw = (f16*)smem + w * 3072;                 // [3][1024]
  f16* Vw = (f16*)(smem + 24576) + w * 3072;       // [3][1024]

  // ---- staging gather addresses (swizzle on the global side) ----
  const int oct = (lane & 7) ^ ((lane >> 3) & 7);
  const f16* kg0 = kh + base + (size_t)(16 * w + (lane >> 3)) * 64 + oct * 8;
  const f16* kg1 = kg0 + 8 * 64;
  const int vd = lane >> 1;
  const int vc = (lane & 1) ^ ((lane >> 3) & 1);
  const f16* vg0 = vt + (size_t)bh * Dc * Sc + (size_t)vd * Sc + 16 * w + vc * 8;
  const f16* vg1 = vg0 + (size_t)32 * Sc;

  auto stage = [&](int kt, int b) {
    gld_lds16(kg0 + (size_t)kt * 4096, Kw + b * 1024);
    gld_lds16(kg1 + (size_t)kt * 4096, Kw + b * 1024 + 512);
    gld_lds16(vg0 + kt * 64, Vw + b * 1024);
    gld_lds16(vg1 + kt * 64, Vw + b * 1024 + 512);
  };

  // ---- fragment LDS offsets (f16 units, constant per lane) ----
  const int koff0 = lq * 64 + ((qd) ^ (lq & 7)) * 8;
  const int koff1 = lq * 64 + ((4 + qd) ^ (lq & 7)) * 8;
  int voff[4];
#pragma unroll
  for (int dt = 0; dt < 4; ++dt)
    voff[dt] = (16 * dt + lq) * 16 + (((qd >> 1) ^ ((lq >> 2) & 1)) << 3) +
               (qd & 1) * 4;

  // ---- Q B-fragments (one-time packed cvt) ----
  const float* qg = qp + base + (size_t)qt * 64 * Dc;
  f16x8 Qf[4][2];
#pragma unroll
  for (int nt = 0; nt < 4; ++nt)
#pragma unroll
    for (int kc = 0; kc < 2; ++kc) {
      const float* p = qg + (16 * nt + lq) * Dc + 32 * kc + 8 * qd;
      f32x4 a = *(const f32x4*)p;
      f32x4 b = *(const f32x4*)(p + 4);
      auto p0 = __builtin_amdgcn_cvt_pkrtz(a.x, a.y);
      auto p1 = __builtin_amdgcn_cvt_pkrtz(a.z, a.w);
      auto p2 = __builtin_amdgcn_cvt_pkrtz(b.x, b.y);
      auto p3 = __builtin_amdgcn_cvt_pkrtz(b.z, b.w);
      f16x8 qf;
      ((decltype(p0)*)&qf)[0] = p0;
      ((decltype(p0)*)&qf)[1] = p1;
      ((decltype(p0)*)&qf)[2] = p2;
      ((decltype(p0)*)&qf)[3] = p3;
      Qf[nt][kc] = qf;
    }

  // pinned zero accumulator source (avoids 16 v_movs/iter re-zeroing C)
  float z0 = 0.f, z1 = 0.f, z2 = 0.f, z3 = 0.f;
  asm volatile("" : "+v"(z0), "+v"(z1), "+v"(z2), "+v"(z3));
  const f32x4 Zc = (f32x4){z0, z1, z2, z3};

  f32x4 Oa[4][4];
  float ls[4];
#pragma unroll
  for (int nt = 0; nt < 4; ++nt) {
    ls[nt] = 0.f;
#pragma unroll
    for (int dt = 0; dt < 4; ++dt) Oa[nt][dt] = (f32x4){0.f, 0.f, 0.f, 0.f};
  }

  stage(0, 0);
  stage(1, 1);
  stage(2, 2);

  // Body kt: vmcnt(WN) [tile kt landed; issued 3 iters ago]; ds_read K,V
  // from buf kt%3; QK -> exp -> PV; then stage(STGKT) into the SAME buffer
  // (reads provably retired by the MFMA operand waits).
#define FA_BODY(BUF, WN, STGKT)                                               \
  {                                                                           \
    asm volatile("s_waitcnt vmcnt(" WN ")" ::: "memory");                     \
    const f16* KB = Kw + (BUF) * 1024;                                        \
    const f16* VB = Vw + (BUF) * 1024;                                        \
    f16x8 K0 = *(const f16x8*)(KB + koff0);                                   \
    f16x8 K1 = *(const f16x8*)(KB + koff1);                                   \
    f16x4 Vf[4];                                                              \
    _Pragma("unroll")                                                         \
    for (int dt = 0; dt < 4; ++dt) Vf[dt] = *(const f16x4*)(VB + voff[dt]);   \
    f32x4 St[4];                                                              \
    _Pragma("unroll")                                                         \
    for (int nt = 0; nt < 4; ++nt) {                                          \
      f32x4 a = __builtin_amdgcn_mfma_f32_16x16x32_f16(K0, Qf[nt][0], Zc, 0, 0, 0); \
      a = __builtin_amdgcn_mfma_f32_16x16x32_f16(K1, Qf[nt][1], a, 0, 0, 0);  \
      St[nt] = a;                                                             \
    }                                                                         \
    f16x4 Pf[4];                                                              \
    _Pragma("unroll")                                                         \
    for (int nt = 0; nt < 4; ++nt) {                                          \
      float e0 = __builtin_amdgcn_exp2f(St[nt].x);                            \
      float e1 = __builtin_amdgcn_exp2f(St[nt].y);                            \
      float e2 = __builtin_amdgcn_exp2f(St[nt].z);                            \
      float e3 = __builtin_amdgcn_exp2f(St[nt].w);                            \
      ls[nt] += (e0 + e1) + (e2 + e3);                                        \
      auto lo = __builtin_amdgcn_cvt_pkrtz(e0, e1);                           \
      auto hi = __builtin_amdgcn_cvt_pkrtz(e2, e3);                           \
      f16x4 p;                                                                \
      ((decltype(lo)*)&p)[0] = lo;                                            \
      ((decltype(lo)*)&p)[1] = hi;                                            \
      Pf[nt] = p;                                                             \
    }                                                                         \
    _Pragma("unroll")                                                         \
    for (int nt = 0; nt < 4; ++nt)                                            \
      _Pragma("unroll")                                                       \
      for (int dt = 0; dt < 4; ++dt)                                          \
        Oa[nt][dt] = __builtin_amdgcn_mfma_f32_16x16x16f16(Pf[nt], Vf[dt],    \
                                                           Oa[nt][dt], 0, 0, 0); \
    asm volatile("" ::: "memory");  /* keep DMA after the reads above */      \
    if ((STGKT) < 32) stage((STGKT), (BUF));                                  \
  }

#pragma unroll 1
  for (int g = 0; g < 10; ++g) {
    const int k0 = 3 * g;
    FA_BODY(0, "8", k0 + 3)    // kt = 3g+0
    FA_BODY(1, "8", k0 + 4)    // kt = 3g+1
    FA_BODY(2, "8", k0 + 5)    // kt = 3g+2  (g=9: STGKT=32 -> skip)
  }
  FA_BODY(0, "4", 32)          // kt = 30
  FA_BODY(1, "0", 32)          // kt = 31

#undef FA_BODY

  // ---- epilogue: row sums + O tree-reduction (staging LDS reused) ----
#pragma unroll
  for (int nt = 0; nt < 4; ++nt) {
    float l = ls[nt];
    l += __shfl_xor(l, 16, 64);
    l += __shfl_xor(l, 32, 64);
    ls[nt] = l;
  }
  __syncthreads();              // all waves done with staging LDS
  if (qd == 0) {
#pragma unroll
    for (int nt = 0; nt < 4; ++nt) Lred[w][16 * nt + lq] = ls[nt];
  }
  float* OsA = (float*)smem;
  float* OsB = (float*)(smem + 16896);
  float* Os = (w & 2) ? OsB : OsA;
  if (!(w & 1)) {
#pragma unroll
    for (int nt = 0; nt < 4; ++nt)
#pragma unroll
      for (int dt = 0; dt < 4; ++dt)
#pragma unroll
        for (int r = 0; r < 4; ++r)
          Os[(16 * nt + 4 * qd + r) * 66 + 16 * dt + lq] = Oa[nt][dt][r];
  }
  __syncthreads();
  if (w & 1) {
#pragma unroll
    for (int nt = 0; nt < 4; ++nt)
#pragma unroll
      for (int dt = 0; dt < 4; ++dt)
#pragma unroll
        for (int r = 0; r < 4; ++r)
          Os[(16 * nt + 4 * qd + r) * 66 + 16 * dt + lq] += Oa[nt][dt][r];
  }
  __syncthreads();

  float* og = out + base + (size_t)qt * 64 * Dc;
#pragma unroll
  for (int r = 0; r < 16; ++r) {
    int row = 16 * w + r;
    float l = Lred[0][row] + Lred[1][row] + Lred[2][row] + Lred[3][row];
    float vo = OsA[row * 66 + lane] + OsB[row * 66 + lane];
    og[(size_t)row * Dc + lane] = vo / l;
  }
}

extern "C" void kernel_launch(void* const* d_in, const int* in_sizes, int n_in,
                              void* d_out, int out_size, void* d_ws, size_t ws_size,
                              hipStream_t stream) {
  const float* q    = (const float*)d_in[0];
  const float* k    = (const float*)d_in[1];
  const float* v    = (const float*)d_in[2];
  const float* temp = (const float*)d_in[3];
  float* out = (float*)d_out;

  f16* kh = (f16*)d_ws;          // 8.4 MB
  f16* vt = kh + NE;             // 8.4 MB

  prep<<<dim3(Bc * Hc * (Sc / 64)), dim3(256), 0, stream>>>(k, v, temp, kh, vt);
  fa12<<<dim3(Bc * Hc * (Sc / 64)), dim3(256), 0, stream>>>(q, kh, vt, out);
}